// Round 1
// baseline (165.201 us; speedup 1.0000x reference)
//
#include <hip/hip_runtime.h>

#define HIDDEN 64
#define SEQLEN 96
#define NB 10
#define BATCH 16384
#define NCLASS 2
#define OSPLIT 8          // o-groups (blockIdx.y)
#define OPER   (HIDDEN / OSPLIT)   // 8 outputs per thread

// tanh(x) = 1 - 2/(e^{2x}+1); exp via hw v_exp, rcp via hw v_rcp.
// |err| ~1e-6, saturates correctly to +/-1 for large |x|.
__device__ __forceinline__ float fast_tanh(float x) {
    float e = __expf(x + x);
    float r = __builtin_amdgcn_rcpf(e + 1.0f);
    return fmaf(-2.0f, r, 1.0f);
}

__global__ __launch_bounds__(256) void kan_rnn_fused(
    const float* __restrict__ x,    // (B, SEQLEN)
    const float* __restrict__ Wx,   // (1, HIDDEN, NB)
    const float* __restrict__ ax,   // (1, NB)
    const float* __restrict__ cx,   // (1, NB)
    const float* __restrict__ Wc,   // (HIDDEN, HIDDEN, NB)
    const float* __restrict__ ac,   // (HIDDEN, NB)
    const float* __restrict__ cc,   // (HIDDEN, NB)
    const float* __restrict__ Wout, // (HIDDEN, NCLASS)
    float* __restrict__ out)        // (B, NCLASS), pre-zeroed
{
    const int b     = blockIdx.x * blockDim.x + threadIdx.x; // batch element
    const int obase = blockIdx.y * OPER;                     // wave-uniform o-range

    // ---- stage 1: h_i from the last timestep only (recurrence is dead) ----
    const float u = x[b * SEQLEN + (SEQLEN - 1)];
    float t[NB];
#pragma unroll
    for (int k = 0; k < NB; ++k)
        t[k] = fast_tanh(fmaf(ax[k], u, cx[k]));

    float acc[OPER];
#pragma unroll
    for (int oo = 0; oo < OPER; ++oo) acc[oo] = 0.0f;

    for (int i = 0; i < HIDDEN; ++i) {
        const float* wxr = Wx + i * NB;            // uniform -> s_load
        float hx = 0.0f;
#pragma unroll
        for (int k = 0; k < NB; ++k)
            hx = fmaf(wxr[k], t[k], hx);
        const float hi = fast_tanh(hx);

        const float* acr = ac + i * NB;
        const float* ccr = cc + i * NB;
        float p[NB];
#pragma unroll
        for (int k = 0; k < NB; ++k)
            p[k] = fast_tanh(fmaf(acr[k], hi, ccr[k]));

        // 80 contiguous uniform floats per i for this o-group
        const float* wcr = Wc + i * (HIDDEN * NB) + obase * NB;
#pragma unroll
        for (int oo = 0; oo < OPER; ++oo) {
#pragma unroll
            for (int k = 0; k < NB; ++k)
                acc[oo] = fmaf(wcr[oo * NB + k], p[k], acc[oo]);
        }
    }

    // ---- epilogue: g = tanh(acc), partial out = g @ Wout, combine via atomics
    float r0 = 0.0f, r1 = 0.0f;
#pragma unroll
    for (int oo = 0; oo < OPER; ++oo) {
        const float g = fast_tanh(acc[oo]);
        const int o = obase + oo;
        r0 = fmaf(g, Wout[o * NCLASS + 0], r0);
        r1 = fmaf(g, Wout[o * NCLASS + 1], r1);
    }
    atomicAdd(&out[b * NCLASS + 0], r0);
    atomicAdd(&out[b * NCLASS + 1], r1);
}

extern "C" void kernel_launch(void* const* d_in, const int* in_sizes, int n_in,
                              void* d_out, int out_size, void* d_ws, size_t ws_size,
                              hipStream_t stream) {
    const float* x    = (const float*)d_in[0];
    const float* Wx   = (const float*)d_in[1];
    const float* ax   = (const float*)d_in[2];
    const float* cx   = (const float*)d_in[3];
    // d_in[4..6] = Wh, ah, ch — dead in the reference (comb[:, :HIDDEN] == tanh(x_phi))
    const float* Wc   = (const float*)d_in[7];
    const float* ac   = (const float*)d_in[8];
    const float* cc   = (const float*)d_in[9];
    const float* Wout = (const float*)d_in[10];
    float* out = (float*)d_out;

    hipMemsetAsync(out, 0, (size_t)out_size * sizeof(float), stream);

    dim3 grid(BATCH / 256, OSPLIT);
    dim3 block(256);
    kan_rnn_fused<<<grid, block, 0, stream>>>(x, Wx, ax, cx, Wc, ac, cc, Wout, out);
}